// Round 20
// baseline (111.381 us; speedup 1.0000x reference)
//
#include <hip/hip_runtime.h>

#define BB 512
#define TT 512
#define KK 128
#define CS 144    // chain stride in shorts: uniform 2-way banks (verified R18: 0 conflicts)
#define NSEG 16
#define SEGL 32
#define WARM 8    // contraction 0.151^8 ~ 3e-7: junction error negligible

typedef __attribute__((ext_vector_type(8))) short short8;   // 8 x bf16 bits
typedef __attribute__((ext_vector_type(4))) float f32x4;

__device__ __forceinline__ unsigned short f2bf(float f) {
  unsigned u = __float_as_uint(f);
  unsigned r = ((u >> 16) & 1u) + 0x7fffu;
  return (unsigned short)((u + r) >> 16);
}
__device__ __forceinline__ float bf2f(unsigned short h) {
  return __uint_as_float(((unsigned)h) << 16);
}

// K1: 512 blocks x 256 threads = 2048 INDEPENDENT single-wave chains.
// Wave (g, s): batch-quad g (batches 4g..4g+3), segment s of NSEG.
// FOUR chains packed in MFMA A-rows (A[row][k] = state[row&3][k], row=lane&15
// -- layout verified R13-R18). ONE wave does the full matvec: 8 col-tiles x
// 4 k-chunks = 32 MFMAs/step. D: row = 4*(lane>>4)+reg -> chain = reg;
// lane (lg,lc) finalizes chain lg, cols j = 16T+lc, T=0..7 (8 outputs/lane).
// NO barriers: LDS double-buffer is wave-private (program-ordered lgkmcnt).
// __launch_bounds__(256, 1): B matrix = 128 VGPRs MUST stay in registers --
// R19's (256,2) made the RA target 128 total and spill B to scratch
// (WRITE_SIZE 14 MB, MfmaUtil 17%). ~210 VGPRs < 256 keeps 2 waves/SIMD.
// Scale exponent d_c comes from the PREVIOUS step's v0 register via
// readlane (no LDS round-trip on the critical path).
// Segment s covers t in (32s, 32(s+1)]; s>0 warms up WARM steps from the
// all-ones state (Hilbert contraction); junctions telescoped in K2 via
// exported (M, state[0]) at warmup end ("mid") and segment end  -- R18-verified.
__global__ __launch_bounds__(256, 1) void crf_seg_kernel(
    const float* __restrict__ pot, const int* __restrict__ tags,
    const float* __restrict__ trans, unsigned short* __restrict__ wsv,
    float* __restrict__ wsm, float* __restrict__ wssc) {
  const float C = 1.4426950408889634f;    // 1/ln2
  const int tid = threadIdx.x;
  const int lane = tid & 63;
  const int wv = tid >> 6;
  const int bid = blockIdx.x;
  const int g = bid >> 2;                 // batch-quad 0..127
  const int s = ((bid & 3) << 2) | wv;    // segment 0..15
  const int lg = lane >> 4;               // lane group (epilogue chain)
  const int lc = lane & 15;
  const int crA = lc & 3;                 // A-row chain

  __shared__ alignas(16) unsigned short sb[4][2][4][CS];  // [wave][parity][chain][j]
  auto* sbw = sb[wv];

  // ---- sequence score: waves s<4 handle batch 4g+s ----
  if (s < 4) {
    int bb = 4 * g + s;
    int base = 8 * lane;
    const float* pbs = pot + (size_t)bb * TT * KK;
    int4 tgA = *(const int4*)&tags[bb * TT + base];
    int4 tgB = *(const int4*)&tags[bb * TT + base + 4];
    float sc =
        pbs[(size_t)(base + 0) * KK + tgA.x] + pbs[(size_t)(base + 1) * KK + tgA.y] +
        pbs[(size_t)(base + 2) * KK + tgA.z] + pbs[(size_t)(base + 3) * KK + tgA.w] +
        pbs[(size_t)(base + 4) * KK + tgB.x] + pbs[(size_t)(base + 5) * KK + tgB.y] +
        pbs[(size_t)(base + 6) * KK + tgB.z] + pbs[(size_t)(base + 7) * KK + tgB.w];
    sc += trans[tgA.x * KK + tgA.y] + trans[tgA.y * KK + tgA.z] +
          trans[tgA.z * KK + tgA.w] + trans[tgA.w * KK + tgB.x] +
          trans[tgB.x * KK + tgB.y] + trans[tgB.y * KK + tgB.z] +
          trans[tgB.z * KK + tgB.w];
    if (base + 8 < TT) sc += trans[tgB.w * KK + tags[bb * TT + base + 8]];
    #pragma unroll
    for (int off = 32; off; off >>= 1) sc += __shfl_xor(sc, off, 64);
    if (lane == 0) wssc[bb] = sc;
  }

  // ---- B fragments: 8 col-tiles x 4 k-chunks (forward E) ----
  short8 Bf[8][4];
  #pragma unroll
  for (int T = 0; T < 8; ++T) {
    const int j = 16 * T + lc;
    #pragma unroll
    for (int kc = 0; kc < 4; ++kc) {
      #pragma unroll
      for (int e = 0; e < 8; ++e) {
        Bf[T][kc][e] =
            (short)f2bf(__builtin_amdgcn_exp2f(trans[(32 * kc + 8 * lg + e) * KK + j] * C));
      }
    }
  }

  const int rstart = (s == 0) ? 1 : (SEGL * s - WARM + 1);
  const int nwarm = (s == 0) ? 0 : WARM;
  const int nmain = (s == NSEG - 1) ? (SEGL - 1) : SEGL;
  const int nsteps = nwarm + nmain;
  const float* ppc = pot + (size_t)(4 * g + lg) * TT * KK;  // chain lg's pot

  // ---- init state at parity 0; v0last tracks this lane's T=0 value ----
  float v0last;
  if (s == 0) {
    float w0T0 = 0.f;
    #pragma unroll
    for (int T = 0; T < 8; ++T) {
      float w0 = __builtin_amdgcn_exp2f(ppc[16 * T + lc] * C);
      if (T == 0) w0T0 = w0;
      sbw[0][lg][16 * T + lc] = f2bf(w0);
    }
    v0last = w0T0;
  } else {
    #pragma unroll
    for (int T = 0; T < 8; ++T)
      sbw[0][lg][16 * T + lc] = 0x3F80;   // bf16 1.0
    v0last = 1.f;
  }

  // ---- pot prefetch: pe = even-step rows, po = odd-step rows ----
  float pe[8], po[8];
  #pragma unroll
  for (int T = 0; T < 8; ++T) {
    pe[T] = ppc[(size_t)rstart * KK + 16 * T + lc];
    po[T] = ppc[(size_t)(rstart + 1) * KK + 16 * T + lc];
  }

  int Mi = 0, MiMid = 0;
  float vMid = 1.f;
  const f32x4 kZero = {0.f, 0.f, 0.f, 0.f};

  auto step = [&](int it, float (&cur)[8]) {
    const int p = it & 1, wr = p ^ 1;
    // d_c = f32 exponent of chain c's col-0 value from LAST step (register,
    // no LDS dependency). Lane 16c holds it (lg=c, lc=0).
    unsigned ub = __float_as_uint(v0last);
    int d0 = (int)((__builtin_amdgcn_readlane(ub, 0)  >> 23) & 0xFF) - 127;
    int d1 = (int)((__builtin_amdgcn_readlane(ub, 16) >> 23) & 0xFF) - 127;
    int d2 = (int)((__builtin_amdgcn_readlane(ub, 32) >> 23) & 0xFF) - 127;
    int d3 = (int)((__builtin_amdgcn_readlane(ub, 48) >> 23) & 0xFF) - 127;
    int dc = (lg == 0) ? d0 : ((lg == 1) ? d1 : ((lg == 2) ? d2 : d3));
    float fd = (float)(-dc);
    const unsigned short* sp = &sbw[p][crA][0];
    short8 A0 = *(const short8*)(sp + 8 * lg);
    short8 A1 = *(const short8*)(sp + 32 + 8 * lg);
    short8 A2 = *(const short8*)(sp + 64 + 8 * lg);
    short8 A3 = *(const short8*)(sp + 96 + 8 * lg);
    int rn = rstart + it + 2;
    if (rn > TT - 1) rn = TT - 1;
    f32x4 a0, a1, a2, a3, a4, a5, a6, a7;
    a0 = __builtin_amdgcn_mfma_f32_16x16x32_bf16(A3, Bf[0][3], kZero, 0, 0, 0);
    a1 = __builtin_amdgcn_mfma_f32_16x16x32_bf16(A3, Bf[1][3], kZero, 0, 0, 0);
    a2 = __builtin_amdgcn_mfma_f32_16x16x32_bf16(A3, Bf[2][3], kZero, 0, 0, 0);
    a3 = __builtin_amdgcn_mfma_f32_16x16x32_bf16(A3, Bf[3][3], kZero, 0, 0, 0);
    a4 = __builtin_amdgcn_mfma_f32_16x16x32_bf16(A3, Bf[4][3], kZero, 0, 0, 0);
    a5 = __builtin_amdgcn_mfma_f32_16x16x32_bf16(A3, Bf[5][3], kZero, 0, 0, 0);
    a6 = __builtin_amdgcn_mfma_f32_16x16x32_bf16(A3, Bf[6][3], kZero, 0, 0, 0);
    a7 = __builtin_amdgcn_mfma_f32_16x16x32_bf16(A3, Bf[7][3], kZero, 0, 0, 0);
    a0 = __builtin_amdgcn_mfma_f32_16x16x32_bf16(A2, Bf[0][2], a0, 0, 0, 0);
    a1 = __builtin_amdgcn_mfma_f32_16x16x32_bf16(A2, Bf[1][2], a1, 0, 0, 0);
    a2 = __builtin_amdgcn_mfma_f32_16x16x32_bf16(A2, Bf[2][2], a2, 0, 0, 0);
    a3 = __builtin_amdgcn_mfma_f32_16x16x32_bf16(A2, Bf[3][2], a3, 0, 0, 0);
    a4 = __builtin_amdgcn_mfma_f32_16x16x32_bf16(A2, Bf[4][2], a4, 0, 0, 0);
    a5 = __builtin_amdgcn_mfma_f32_16x16x32_bf16(A2, Bf[5][2], a5, 0, 0, 0);
    a6 = __builtin_amdgcn_mfma_f32_16x16x32_bf16(A2, Bf[6][2], a6, 0, 0, 0);
    a7 = __builtin_amdgcn_mfma_f32_16x16x32_bf16(A2, Bf[7][2], a7, 0, 0, 0);
    a0 = __builtin_amdgcn_mfma_f32_16x16x32_bf16(A1, Bf[0][1], a0, 0, 0, 0);
    a1 = __builtin_amdgcn_mfma_f32_16x16x32_bf16(A1, Bf[1][1], a1, 0, 0, 0);
    a2 = __builtin_amdgcn_mfma_f32_16x16x32_bf16(A1, Bf[2][1], a2, 0, 0, 0);
    a3 = __builtin_amdgcn_mfma_f32_16x16x32_bf16(A1, Bf[3][1], a3, 0, 0, 0);
    a4 = __builtin_amdgcn_mfma_f32_16x16x32_bf16(A1, Bf[4][1], a4, 0, 0, 0);
    a5 = __builtin_amdgcn_mfma_f32_16x16x32_bf16(A1, Bf[5][1], a5, 0, 0, 0);
    a6 = __builtin_amdgcn_mfma_f32_16x16x32_bf16(A1, Bf[6][1], a6, 0, 0, 0);
    a7 = __builtin_amdgcn_mfma_f32_16x16x32_bf16(A1, Bf[7][1], a7, 0, 0, 0);
    a0 = __builtin_amdgcn_mfma_f32_16x16x32_bf16(A0, Bf[0][0], a0, 0, 0, 0);
    a1 = __builtin_amdgcn_mfma_f32_16x16x32_bf16(A0, Bf[1][0], a1, 0, 0, 0);
    a2 = __builtin_amdgcn_mfma_f32_16x16x32_bf16(A0, Bf[2][0], a2, 0, 0, 0);
    a3 = __builtin_amdgcn_mfma_f32_16x16x32_bf16(A0, Bf[3][0], a3, 0, 0, 0);
    a4 = __builtin_amdgcn_mfma_f32_16x16x32_bf16(A0, Bf[4][0], a4, 0, 0, 0);
    a5 = __builtin_amdgcn_mfma_f32_16x16x32_bf16(A0, Bf[5][0], a5, 0, 0, 0);
    a6 = __builtin_amdgcn_mfma_f32_16x16x32_bf16(A0, Bf[6][0], a6, 0, 0, 0);
    a7 = __builtin_amdgcn_mfma_f32_16x16x32_bf16(A0, Bf[7][0], a7, 0, 0, 0);
    // epilogue: lane takes chain lg (acc reg lg) of each tile
    #pragma unroll
    for (int T = 0; T < 8; ++T) {
      f32x4 aT = (T == 0) ? a0 : (T == 1) ? a1 : (T == 2) ? a2 : (T == 3) ? a3
               : (T == 4) ? a4 : (T == 5) ? a5 : (T == 6) ? a6 : a7;
      float z = (lg == 0) ? aT[0] : ((lg == 1) ? aT[1] : ((lg == 2) ? aT[2] : aT[3]));
      float u = cur[T];
      cur[T] = ppc[(size_t)rn * KK + 16 * T + lc];   // reload for step it+2
      float v = z * __builtin_amdgcn_exp2f(fmaf(u, C, fd));
      if (T == 0) v0last = v;
      sbw[wr][lg][16 * T + lc] = f2bf(v);
    }
    Mi += dc;
  };

  int it = 0;
  if (s > 0) {                            // warmup: 8 steps, capture "mid"
    #pragma unroll
    for (int q = 0; q < WARM / 2; ++q) {
      step(it, pe); ++it;
      step(it, po); ++it;
    }
    vMid = v0last; MiMid = Mi;
  }
  while (it + 1 < nsteps) {
    step(it, pe); ++it;
    step(it, po); ++it;
  }
  if (it < nsteps) { step(it, pe); ++it; }

  // ---- export junction scalars (lanes lc==0; chain = lg) ----
  if (lc == 0) {
    float* jp = &wsm[(((size_t)g * NSEG + s) * 4 + lg) * 4];
    jp[0] = (float)MiMid;   // M at warmup end
    jp[1] = vMid;           // state[0] at warmup end
    jp[2] = (float)Mi;      // M at segment end
    jp[3] = v0last;         // state[0] at segment end
  }
  // ---- last segment: export final state vectors ----
  if (s == NSEG - 1) {
    const int fin = nsteps & 1;           // 39 -> parity 1
    #pragma unroll
    for (int T = 0; T < 8; ++T)
      wsv[(size_t)(4 * g + lg) * KK + 16 * T + lc] = sbw[fin][lg][16 * T + lc];
  }
}

// K2: per batch: logZ2 = M_end(15) + log2(sum w15) + telescoped junctions.
__global__ __launch_bounds__(256) void crf_combine_kernel(
    const unsigned short* __restrict__ wsv, const float* __restrict__ wsm,
    const float* __restrict__ wssc, float* __restrict__ out) {
  const float LN2 = 0.6931471805599453f;
  const int tid = threadIdx.x;
  const int lane = tid & 63, wid = tid >> 6;
  const int b = blockIdx.x * 4 + wid;     // 128 blocks x 4 waves = 512
  const int g = b >> 2, c = b & 3;
  const unsigned short* vf = wsv + (size_t)b * KK;
  float sum = bf2f(vf[lane]) + bf2f(vf[lane + 64]);
  #pragma unroll
  for (int off = 32; off; off >>= 1) sum += __shfl_xor(sum, off, 64);
  if (lane == 0) {
    auto SC = [&](int s, int k) {
      return wsm[(((size_t)g * NSEG + s) * 4 + c) * 4 + k];
    };
    float l2 = SC(NSEG - 1, 2) + __builtin_amdgcn_logf(sum);  // v_log = log2
    #pragma unroll
    for (int s = 1; s < NSEG; ++s) {
      l2 += SC(s - 1, 2) + __builtin_amdgcn_logf(SC(s - 1, 3));
      l2 -= SC(s, 0) + __builtin_amdgcn_logf(SC(s, 1));
    }
    out[b] = wssc[b] - l2 * LN2;
  }
}

extern "C" void kernel_launch(void* const* d_in, const int* in_sizes, int n_in,
                              void* d_out, int out_size, void* d_ws, size_t ws_size,
                              hipStream_t stream) {
  const float* pot = (const float*)d_in[0];
  const int* tags = (const int*)d_in[1];
  const float* trans = (const float*)d_in[2];
  float* out = (float*)d_out;
  unsigned short* wsv = (unsigned short*)d_ws;                  // 512 x 128 bf16
  float* wsm = (float*)((char*)d_ws + (size_t)BB * KK * 2);     // 128x16x4 x 4 f32
  float* wssc = (float*)((char*)d_ws + (size_t)BB * KK * 2 +
                         (size_t)128 * NSEG * 4 * 4 * 4);       // 512 f32
  crf_seg_kernel<<<512, 256, 0, stream>>>(pot, tags, trans, wsv, wsm, wssc);
  crf_combine_kernel<<<BB / 4, 256, 0, stream>>>(wsv, wsm, wssc, out);
}

// Round 21
// 80.554 us; speedup vs baseline: 1.3827x; 1.3827x over previous
//
#include <hip/hip_runtime.h>

#define BB 512
#define TT 512
#define KK 128
#define CS 144    // chain stride in shorts: uniform 2-way banks (verified R18: 0 conflicts)
#define NSEG 16
#define SEGL 32
#define WARM 8    // contraction 0.151^8 ~ 3e-7: junction error negligible

typedef __attribute__((ext_vector_type(8))) short short8;   // 8 x bf16 bits
typedef __attribute__((ext_vector_type(4))) float f32x4;

__device__ __forceinline__ unsigned short f2bf(float f) {
  unsigned u = __float_as_uint(f);
  unsigned r = ((u >> 16) & 1u) + 0x7fffu;
  return (unsigned short)((u + r) >> 16);
}
__device__ __forceinline__ float bf2f(unsigned short h) {
  return __uint_as_float(((unsigned)h) << 16);
}
// Drain LDS ops only; global prefetch loads stay in flight across the barrier.
__device__ __forceinline__ void lds_barrier() {
  asm volatile("s_waitcnt lgkmcnt(0)\n\ts_barrier" ::: "memory");
}

// K1: one block per (batch-quad g, segment s). 256 threads = 4 waves.
// NSEG=16 x 128 quads = 2048 blocks = 8 blocks/CU (vs R18's 4): the step
// latency (~2800 cyc) is the wall, not any pipe (LDS 27%, MFMA 10% at R18's
// depth) -- doubling independent blocks/CU doubles overlap at constant total
// chain-steps (NSEG*(SEGL+WARM) = 640/batch, same as R18's 8*80).
// FOUR chains (batches 4g..4g+3) packed into MFMA A-rows: A[row][k] =
// state[row&3][k]. Wave wv owns col-tiles {2wv, 2wv+1}: 8 MFMAs/wave/step
// (two 2-deep chains per tile). D: row = 4*(lane>>4)+reg -> chain = reg.
// Lane (wv,lg,lc) finalizes chain lg, cols jA=32wv+lc, jB=jA+16.
// Segment s covers t in (32s, 32(s+1)]; s>0 starts WARM=8 steps early from
// the all-ones state (Hilbert contraction tau~0.15/step; diag(u) isometry);
// junctions telescope exactly in K2 via exported (M, state[0]) at warmup-end
// ("mid") and segment end -- scheme verified R18 (absmax 16).
// Scaled bf16 state in LDS (stride CS=144: uniform 2-way banks, 0 conflicts);
// lagged power-of-2 rescale: stored_new = matvec * 2^(pot*C - d_c),
// d_c = exponent of state[c][0] (readlane from A0 bf16 bits, no LDS ops).
__global__ __launch_bounds__(256, 4) void crf_seg_kernel(
    const float* __restrict__ pot, const int* __restrict__ tags,
    const float* __restrict__ trans, unsigned short* __restrict__ wsv,
    float* __restrict__ wsm) {
  const float C = 1.4426950408889634f;    // 1/ln2
  const int bid = blockIdx.x;
  const int g = bid >> 4, s = bid & 15;   // batch-quad, segment
  const int tid = threadIdx.x;            // 0..255
  const int lane = tid & 63;
  const int wv = tid >> 6;                // wave -> col-tiles 2wv, 2wv+1
  const int lg = lane >> 4;               // lane group = epilogue chain
  const int lc = lane & 15;               // col within 16-tile
  const int crA = lc & 3;                 // A-row chain

  __shared__ alignas(16) unsigned short sbuf[2][4][CS];  // [parity][chain][j]

  // ---- sequence scores: s==0 blocks only; wave wv covers batch 4g+wv ----
  if (s == 0) {
    int bb = 4 * g + wv;
    int base = 8 * lane;
    const float* pbs = pot + (size_t)bb * TT * KK;
    int4 tgA = *(const int4*)&tags[bb * TT + base];
    int4 tgB = *(const int4*)&tags[bb * TT + base + 4];
    float sc =
        pbs[(size_t)(base + 0) * KK + tgA.x] + pbs[(size_t)(base + 1) * KK + tgA.y] +
        pbs[(size_t)(base + 2) * KK + tgA.z] + pbs[(size_t)(base + 3) * KK + tgA.w] +
        pbs[(size_t)(base + 4) * KK + tgB.x] + pbs[(size_t)(base + 5) * KK + tgB.y] +
        pbs[(size_t)(base + 6) * KK + tgB.z] + pbs[(size_t)(base + 7) * KK + tgB.w];
    sc += trans[tgA.x * KK + tgA.y] + trans[tgA.y * KK + tgA.z] +
          trans[tgA.z * KK + tgA.w] + trans[tgA.w * KK + tgB.x] +
          trans[tgB.x * KK + tgB.y] + trans[tgB.y * KK + tgB.z] +
          trans[tgB.z * KK + tgB.w];
    if (base + 8 < TT) sc += trans[tgB.w * KK + tags[bb * TT + base + 8]];
    #pragma unroll
    for (int off = 32; off; off >>= 1) sc += __shfl_xor(sc, off, 64);
    if (lane == 0) wsm[((size_t)bid * 4 + wv) * 8 + 4] = sc;
  }

  // ---- B fragments: 2 tiles x 4 k-chunks (forward E for everyone) ----
  short8 Bf[2][4];
  #pragma unroll
  for (int t = 0; t < 2; ++t) {
    const int j = 32 * wv + 16 * t + lc;
    #pragma unroll
    for (int kc = 0; kc < 4; ++kc) {
      #pragma unroll
      for (int e = 0; e < 8; ++e) {
        int k = 32 * kc + 8 * lg + e;
        Bf[t][kc][e] = (short)f2bf(__builtin_amdgcn_exp2f(trans[k * KK + j] * C));
      }
    }
  }

  // ---- init: s==0 from u_0; s>0 from all-ones (bf16 1.0) ----
  {
    int c = tid >> 6, j = tid & 63;
    if (s == 0) {
      const float* pi = pot + (size_t)(4 * g + c) * TT * KK;   // row 0
      sbuf[0][c][j]      = f2bf(__builtin_amdgcn_exp2f(pi[j] * C));
      sbuf[0][c][j + 64] = f2bf(__builtin_amdgcn_exp2f(pi[j + 64] * C));
    } else {
      sbuf[0][c][j] = 0x3F80;
      sbuf[0][c][j + 64] = 0x3F80;
    }
  }
  __syncthreads();

  const int r0 = (s == 0) ? 1 : (SEGL * s - WARM + 1);
  const int jA = 32 * wv + lc, jB = jA + 16;
  const float* pp = pot + (size_t)(4 * g + lg) * TT * KK;   // chain lg's pot
  int Mi = 0;
  float lastVA = 1.f;
  const f32x4 kZero = {0.f, 0.f, 0.f, 0.f};

  // 4-phase pot pipeline, two floats per phase (2 cols per lane)
  float p0a = pp[(size_t)(r0 + 0) * KK + jA], p0b = pp[(size_t)(r0 + 0) * KK + jB];
  float p1a = pp[(size_t)(r0 + 1) * KK + jA], p1b = pp[(size_t)(r0 + 1) * KK + jB];
  float p2a = pp[(size_t)(r0 + 2) * KK + jA], p2b = pp[(size_t)(r0 + 2) * KK + jB];
  float p3a = pp[(size_t)(r0 + 3) * KK + jA], p3b = pp[(size_t)(r0 + 3) * KK + jB];

  auto step = [&](int it, float& qa, float& qb) {
    const int p = it & 1, wr = p ^ 1;
    const unsigned short* sp = &sbuf[p][crA][8 * lg];
    short8 A0 = *(const short8*)(sp);        // k =      8lg+e
    short8 A1 = *(const short8*)(sp + 32);   // k = 32 + 8lg+e
    short8 A2 = *(const short8*)(sp + 64);
    short8 A3 = *(const short8*)(sp + 96);
    // d_c = exponent of state[c][0]; lanes 0..3 (lg=0, lc=0..3) hold them
    int e0 = (int)(unsigned short)A0[0];
    int d0 = ((__builtin_amdgcn_readlane(e0, 0) >> 7) & 0xFF) - 127;
    int d1 = ((__builtin_amdgcn_readlane(e0, 1) >> 7) & 0xFF) - 127;
    int d2 = ((__builtin_amdgcn_readlane(e0, 2) >> 7) & 0xFF) - 127;
    int d3 = ((__builtin_amdgcn_readlane(e0, 3) >> 7) & 0xFF) - 127;
    float cpa = qa, cpb = qb;                // pot loaded 4 steps ago
    int rn = r0 + it + 4;
    rn = (rn > TT - 1) ? (TT - 1) : rn;      // s==15 tail clamp
    qa = pp[(size_t)rn * KK + jA];
    qb = pp[(size_t)rn * KK + jB];
    f32x4 aP0, aQ0, aP1, aQ1;                // 2 tiles x two 2-deep chains
    __builtin_amdgcn_s_setprio(1);
    aP0 = __builtin_amdgcn_mfma_f32_16x16x32_bf16(A3, Bf[0][3], kZero, 0, 0, 0);
    aQ0 = __builtin_amdgcn_mfma_f32_16x16x32_bf16(A1, Bf[0][1], kZero, 0, 0, 0);
    aP1 = __builtin_amdgcn_mfma_f32_16x16x32_bf16(A3, Bf[1][3], kZero, 0, 0, 0);
    aQ1 = __builtin_amdgcn_mfma_f32_16x16x32_bf16(A1, Bf[1][1], kZero, 0, 0, 0);
    aP0 = __builtin_amdgcn_mfma_f32_16x16x32_bf16(A2, Bf[0][2], aP0, 0, 0, 0);
    aQ0 = __builtin_amdgcn_mfma_f32_16x16x32_bf16(A0, Bf[0][0], aQ0, 0, 0, 0);
    aP1 = __builtin_amdgcn_mfma_f32_16x16x32_bf16(A2, Bf[1][2], aP1, 0, 0, 0);
    aQ1 = __builtin_amdgcn_mfma_f32_16x16x32_bf16(A0, Bf[1][0], aQ1, 0, 0, 0);
    __builtin_amdgcn_s_setprio(0);
    f32x4 s0 = aP0 + aQ0, s1 = aP1 + aQ1;
    // D reg r = chain r; this lane takes chain lg
    float zA = (lg == 0) ? s0[0] : ((lg == 1) ? s0[1] : ((lg == 2) ? s0[2] : s0[3]));
    float zB = (lg == 0) ? s1[0] : ((lg == 1) ? s1[1] : ((lg == 2) ? s1[2] : s1[3]));
    int dc = (lg == 0) ? d0 : ((lg == 1) ? d1 : ((lg == 2) ? d2 : d3));
    float fd = (float)(-dc);
    float vA = zA * __builtin_amdgcn_exp2f(fmaf(cpa, C, fd));
    float vB = zB * __builtin_amdgcn_exp2f(fmaf(cpb, C, fd));
    Mi += dc;
    lastVA = vA;
    sbuf[wr][lg][jA] = f2bf(vA);
    sbuf[wr][lg][jB] = f2bf(vB);
    lds_barrier();   // lgkmcnt(0)+s_barrier; global loads stay in flight
  };

  // ---- warmup (s>0): 8 steps, then capture the "mid" junction values ----
  float vMid = 1.f; int MiMid = 0;
  if (s > 0) {
    for (int itq = 0; itq < WARM / 4; ++itq) {
      int it = itq << 2;
      step(it + 0, p0a, p0b);
      step(it + 1, p1a, p1b);
      step(it + 2, p2a, p2b);
      step(it + 3, p3a, p3b);
    }
    vMid = lastVA; MiMid = Mi;     // state w_{32s} (shifted), scale M
  }
  // ---- main segment: 32 steps (s<15) / 31 steps (s==15) ----
  const int base2 = (s > 0) ? WARM : 0;
  const int mainGroups = (s == NSEG - 1) ? 7 : 8;
  for (int itq = 0; itq < mainGroups; ++itq) {
    int it = base2 + (itq << 2);
    step(it + 0, p0a, p0b);
    step(it + 1, p1a, p1b);
    step(it + 2, p2a, p2b);
    step(it + 3, p3a, p3b);
  }
  if (s == NSEG - 1) {             // tail: 3 steps (t = 509, 510, 511)
    step(base2 + 28, p0a, p0b);
    step(base2 + 29, p1a, p1b);
    step(base2 + 30, p2a, p2b);
  }

  // ---- export junction scalars (lanes wv==0, lc==0; lg = chain) ----
  if (wv == 0 && lc == 0) {
    size_t ci = ((size_t)bid * 4 + lg) * 8;
    wsm[ci + 0] = (float)MiMid;    // M at warmup end (s>0)
    wsm[ci + 1] = vMid;            // state[0] at warmup end (s>0)
    wsm[ci + 2] = (float)Mi;       // M at segment end
    wsm[ci + 3] = lastVA;          // state[0] at segment end
  }
  // ---- s==15: export final state vector for the LSE ----
  if (s == NSEG - 1) {
    const int nst = WARM + SEGL - 1;   // 39 -> final parity 1
    const int fin = nst & 1;
    int c = tid >> 6, j = tid & 63;
    wsv[((size_t)(g * 4) + c) * KK + j]      = sbuf[fin][c][j];
    wsv[((size_t)(g * 4) + c) * KK + j + 64] = sbuf[fin][c][j + 64];
  }
}

// K2: per batch: logZ2 = M_end(15) + log2(sum w15) + telescoped junctions.
__global__ __launch_bounds__(256) void crf_combine_kernel(
    const unsigned short* __restrict__ wsv, const float* __restrict__ wsm,
    float* __restrict__ out) {
  const float LN2 = 0.6931471805599453f;
  const int tid = threadIdx.x;
  const int lane = tid & 63, wid = tid >> 6;
  const int b = blockIdx.x * 4 + wid;      // 128 blocks x 4 waves = 512
  const int g = b >> 2, c = b & 3;
  const unsigned short* v15 = wsv + ((size_t)(g * 4) + c) * KK;
  float sum = bf2f(v15[lane]) + bf2f(v15[lane + 64]);
  #pragma unroll
  for (int off = 32; off; off >>= 1) sum += __shfl_xor(sum, off, 64);
  if (lane == 0) {
    auto SC = [&](int s, int k) {
      return wsm[(((size_t)(g * NSEG + s)) * 4 + c) * 8 + k];
    };
    float logZ2 = SC(NSEG - 1, 2) + __builtin_amdgcn_logf(sum);   // v_log = log2
    #pragma unroll
    for (int s = 1; s < NSEG; ++s) {
      logZ2 += SC(s - 1, 2) + __builtin_amdgcn_logf(SC(s - 1, 3));
      logZ2 -= SC(s, 0) + __builtin_amdgcn_logf(SC(s, 1));
    }
    out[b] = SC(0, 4) - logZ2 * LN2;
  }
}

extern "C" void kernel_launch(void* const* d_in, const int* in_sizes, int n_in,
                              void* d_out, int out_size, void* d_ws, size_t ws_size,
                              hipStream_t stream) {
  const float* pot = (const float*)d_in[0];
  const int* tags = (const int*)d_in[1];
  const float* trans = (const float*)d_in[2];
  float* out = (float*)d_out;
  unsigned short* wsv = (unsigned short*)d_ws;                  // 512 x 128 bf16
  float* wsm = (float*)((char*)d_ws + (size_t)BB * KK * 2);     // 2048x4 x 8 f32
  crf_seg_kernel<<<128 * NSEG, 256, 0, stream>>>(pot, tags, trans, wsv, wsm);
  crf_combine_kernel<<<BB / 4, 256, 0, stream>>>(wsv, wsm, out);
}

// Round 22
// 74.852 us; speedup vs baseline: 1.4880x; 1.0762x over previous
//
#include <hip/hip_runtime.h>

#define BB 512
#define TT 512
#define KK 128
#define CS 144    // chain stride in shorts: 72 dw == +8 banks per chain -> uniform 2-way
#define WARM 8    // warmup steps; contraction 0.151^8 ~ 3e-7 (R18 used 16 -- 2x more than needed)
#define CUT 64    // segment length

typedef __attribute__((ext_vector_type(8))) short short8;   // 8 x bf16 bits
typedef __attribute__((ext_vector_type(4))) float f32x4;

// f32 -> bf16 bits, round-to-nearest-even (finite values)
__device__ __forceinline__ unsigned short f2bf(float f) {
  unsigned u = __float_as_uint(f);
  unsigned r = ((u >> 16) & 1u) + 0x7fffu;
  return (unsigned short)((u + r) >> 16);
}
__device__ __forceinline__ float bf2f(unsigned short h) {
  return __uint_as_float(((unsigned)h) << 16);
}
// Drain LDS ops only; global prefetch loads stay in flight across the barrier.
__device__ __forceinline__ void lds_barrier() {
  asm volatile("s_waitcnt lgkmcnt(0)\n\ts_barrier" ::: "memory");
}

// K1: one block per (batch-quad g, segment s). 256 threads = 4 waves.
// (R18 structure verified at 75.0 us / absmax 16; only WARM halved 16->8.)
// FOUR chains (batches 4g..4g+3, all running segment s FORWARD) packed into
// MFMA A-rows: A[row][k] = state[row&3][k] (A layout: row = lane&15).
// Wave wv owns col-tiles {2wv, 2wv+1}: 8 MFMAs/wave/step serve 4 chains
// = 8 MFMAs per chain-step. D layout: row = 4*(lane>>4)+reg -> chain = reg.
// Lane (wv,lg,lc) finalizes chain lg, cols jA=32wv+lc and jB=jA+16.
// Segment s covers steps t in (64s, 64(s+1)]; s>0 starts W=8 steps early
// from the ALL-ONES state: the DP map is a Hilbert-metric contraction
// (tau~0.15/step; diag(u) is an isometry), so after W steps the state equals
// the true state up to a constant shift, which telescopes exactly in K2 via
// the exported (M, state[0]) pairs at warmup-end ("mid") and end.
// Scaled bf16 state in LDS (stride CS=144: uniform 2-way banks = free);
// lagged power-of-2 rescale: stored_new = matvec * 2^(pot*C - d_c),
// d_c = exponent of state[c][0] (readlane from A0, no LDS); M_c += d_c.
__global__ __launch_bounds__(256, 4) void crf_seg_kernel(
    const float* __restrict__ pot, const int* __restrict__ tags,
    const float* __restrict__ trans, unsigned short* __restrict__ wsv,
    float* __restrict__ wsm) {
  const float C = 1.4426950408889634f;    // 1/ln2
  const int bid = blockIdx.x;
  const int g = bid >> 3, s = bid & 7;    // batch-quad, segment
  const int tid = threadIdx.x;            // 0..255
  const int lane = tid & 63;
  const int wv = tid >> 6;                // wave -> col-tiles 2wv, 2wv+1
  const int lg = lane >> 4;               // lane group = epilogue chain
  const int lc = lane & 15;               // col within 16-tile
  const int crA = lc & 3;                 // A-row chain

  __shared__ alignas(16) unsigned short sbuf[2][4][CS];  // [parity][chain][j]

  // ---- sequence scores: s==0 blocks only; wave wv covers batch 4g+wv ----
  if (s == 0) {
    int bb = 4 * g + wv;
    int base = 8 * lane;
    const float* pbs = pot + (size_t)bb * TT * KK;
    int4 tgA = *(const int4*)&tags[bb * TT + base];
    int4 tgB = *(const int4*)&tags[bb * TT + base + 4];
    float sc =
        pbs[(size_t)(base + 0) * KK + tgA.x] + pbs[(size_t)(base + 1) * KK + tgA.y] +
        pbs[(size_t)(base + 2) * KK + tgA.z] + pbs[(size_t)(base + 3) * KK + tgA.w] +
        pbs[(size_t)(base + 4) * KK + tgB.x] + pbs[(size_t)(base + 5) * KK + tgB.y] +
        pbs[(size_t)(base + 6) * KK + tgB.z] + pbs[(size_t)(base + 7) * KK + tgB.w];
    sc += trans[tgA.x * KK + tgA.y] + trans[tgA.y * KK + tgA.z] +
          trans[tgA.z * KK + tgA.w] + trans[tgA.w * KK + tgB.x] +
          trans[tgB.x * KK + tgB.y] + trans[tgB.y * KK + tgB.z] +
          trans[tgB.z * KK + tgB.w];
    if (base + 8 < TT) sc += trans[tgB.w * KK + tags[bb * TT + base + 8]];
    #pragma unroll
    for (int off = 32; off; off >>= 1) sc += __shfl_xor(sc, off, 64);
    if (lane == 0) wsm[((size_t)bid * 4 + wv) * 8 + 4] = sc;
  }

  // ---- B fragments: 2 tiles x 4 k-chunks (forward E for everyone) ----
  short8 Bf[2][4];
  #pragma unroll
  for (int t = 0; t < 2; ++t) {
    const int j = 32 * wv + 16 * t + lc;
    #pragma unroll
    for (int kc = 0; kc < 4; ++kc) {
      #pragma unroll
      for (int e = 0; e < 8; ++e) {
        int k = 32 * kc + 8 * lg + e;
        Bf[t][kc][e] = (short)f2bf(__builtin_amdgcn_exp2f(trans[k * KK + j] * C));
      }
    }
  }

  // ---- init: s==0 from u_0; s>0 from all-ones (bf16 1.0) ----
  {
    int c = tid >> 6, j = tid & 63;
    if (s == 0) {
      const float* pi = pot + (size_t)(4 * g + c) * TT * KK;   // row 0
      sbuf[0][c][j]      = f2bf(__builtin_amdgcn_exp2f(pi[j] * C));
      sbuf[0][c][j + 64] = f2bf(__builtin_amdgcn_exp2f(pi[j + 64] * C));
    } else {
      sbuf[0][c][j] = 0x3F80;
      sbuf[0][c][j + 64] = 0x3F80;
    }
  }
  __syncthreads();

  const int r0 = (s == 0) ? 1 : (CUT * s - WARM + 1);
  const int jA = 32 * wv + lc, jB = jA + 16;
  const float* pp = pot + (size_t)(4 * g + lg) * TT * KK;   // chain lg's pot
  int Mi = 0;
  float lastVA = 1.f;
  const f32x4 kZero = {0.f, 0.f, 0.f, 0.f};

  // 4-phase pot pipeline, two floats per phase (2 cols per lane)
  float p0a = pp[(size_t)(r0 + 0) * KK + jA], p0b = pp[(size_t)(r0 + 0) * KK + jB];
  float p1a = pp[(size_t)(r0 + 1) * KK + jA], p1b = pp[(size_t)(r0 + 1) * KK + jB];
  float p2a = pp[(size_t)(r0 + 2) * KK + jA], p2b = pp[(size_t)(r0 + 2) * KK + jB];
  float p3a = pp[(size_t)(r0 + 3) * KK + jA], p3b = pp[(size_t)(r0 + 3) * KK + jB];

  auto step = [&](int it, float& qa, float& qb) {
    const int p = it & 1, wr = p ^ 1;
    const unsigned short* sp = &sbuf[p][crA][8 * lg];
    short8 A0 = *(const short8*)(sp);        // k =      8lg+e
    short8 A1 = *(const short8*)(sp + 32);   // k = 32 + 8lg+e
    short8 A2 = *(const short8*)(sp + 64);
    short8 A3 = *(const short8*)(sp + 96);
    // d_c = exponent of state[c][0]; lanes 0..3 (lg=0, lc=0..3) hold them
    int e0 = (int)(unsigned short)A0[0];
    int d0 = ((__builtin_amdgcn_readlane(e0, 0) >> 7) & 0xFF) - 127;
    int d1 = ((__builtin_amdgcn_readlane(e0, 1) >> 7) & 0xFF) - 127;
    int d2 = ((__builtin_amdgcn_readlane(e0, 2) >> 7) & 0xFF) - 127;
    int d3 = ((__builtin_amdgcn_readlane(e0, 3) >> 7) & 0xFF) - 127;
    float cpa = qa, cpb = qb;                // pot loaded 4 steps ago
    int rn = r0 + it + 4;
    rn = (rn > TT - 1) ? (TT - 1) : rn;      // s==7 tail clamp
    qa = pp[(size_t)rn * KK + jA];
    qb = pp[(size_t)rn * KK + jB];
    f32x4 aP0, aQ0, aP1, aQ1;                // 2 tiles x two 2-deep chains
    __builtin_amdgcn_s_setprio(1);
    aP0 = __builtin_amdgcn_mfma_f32_16x16x32_bf16(A3, Bf[0][3], kZero, 0, 0, 0);
    aQ0 = __builtin_amdgcn_mfma_f32_16x16x32_bf16(A1, Bf[0][1], kZero, 0, 0, 0);
    aP1 = __builtin_amdgcn_mfma_f32_16x16x32_bf16(A3, Bf[1][3], kZero, 0, 0, 0);
    aQ1 = __builtin_amdgcn_mfma_f32_16x16x32_bf16(A1, Bf[1][1], kZero, 0, 0, 0);
    aP0 = __builtin_amdgcn_mfma_f32_16x16x32_bf16(A2, Bf[0][2], aP0, 0, 0, 0);
    aQ0 = __builtin_amdgcn_mfma_f32_16x16x32_bf16(A0, Bf[0][0], aQ0, 0, 0, 0);
    aP1 = __builtin_amdgcn_mfma_f32_16x16x32_bf16(A2, Bf[1][2], aP1, 0, 0, 0);
    aQ1 = __builtin_amdgcn_mfma_f32_16x16x32_bf16(A0, Bf[1][0], aQ1, 0, 0, 0);
    __builtin_amdgcn_s_setprio(0);
    f32x4 s0 = aP0 + aQ0, s1 = aP1 + aQ1;
    // D reg r = chain r; this lane takes chain lg
    float zA = (lg == 0) ? s0[0] : ((lg == 1) ? s0[1] : ((lg == 2) ? s0[2] : s0[3]));
    float zB = (lg == 0) ? s1[0] : ((lg == 1) ? s1[1] : ((lg == 2) ? s1[2] : s1[3]));
    int dc = (lg == 0) ? d0 : ((lg == 1) ? d1 : ((lg == 2) ? d2 : d3));
    float fd = (float)(-dc);
    float vA = zA * __builtin_amdgcn_exp2f(fmaf(cpa, C, fd));
    float vB = zB * __builtin_amdgcn_exp2f(fmaf(cpb, C, fd));
    Mi += dc;
    lastVA = vA;
    sbuf[wr][lg][jA] = f2bf(vA);
    sbuf[wr][lg][jB] = f2bf(vB);
    lds_barrier();   // lgkmcnt(0)+s_barrier; global loads stay in flight
  };

  // ---- warmup (s>0): 8 steps, then capture the "mid" junction values ----
  float vMid = 1.f; int MiMid = 0;
  if (s > 0) {
    for (int itq = 0; itq < WARM / 4; ++itq) {
      int it = itq << 2;
      step(it + 0, p0a, p0b);
      step(it + 1, p1a, p1b);
      step(it + 2, p2a, p2b);
      step(it + 3, p3a, p3b);
    }
    vMid = lastVA; MiMid = Mi;     // state w_{64s} (shifted), scale M
  }
  // ---- main segment: 64 steps (s<7) / 63 steps (s==7) ----
  const int base2 = (s > 0) ? WARM : 0;
  const int mainGroups = (s == 7) ? 15 : 16;
  for (int itq = 0; itq < mainGroups; ++itq) {
    int it = base2 + (itq << 2);
    step(it + 0, p0a, p0b);
    step(it + 1, p1a, p1b);
    step(it + 2, p2a, p2b);
    step(it + 3, p3a, p3b);
  }
  if (s == 7) {                    // tail: 3 steps (t = 509, 510, 511)
    step(base2 + 60, p0a, p0b);    // (base2+60) % 4 == 0 -> phase p0 ✓
    step(base2 + 61, p1a, p1b);
    step(base2 + 62, p2a, p2b);
  }

  // ---- export junction scalars (lanes wv==0, lc==0; lg = chain) ----
  if (wv == 0 && lc == 0) {
    size_t ci = ((size_t)bid * 4 + lg) * 8;
    wsm[ci + 0] = (float)MiMid;    // M at warmup end (s>0)
    wsm[ci + 1] = vMid;            // state[0] at warmup end (s>0)
    wsm[ci + 2] = (float)Mi;       // M at segment end
    wsm[ci + 3] = lastVA;          // state[0] at segment end
  }
  // ---- s==7: export final state vector for the LSE ----
  if (s == 7) {
    const int nst = WARM + 63;     // 71 -> final parity 1
    const int fin = nst & 1;
    int c = tid >> 6, j = tid & 63;
    wsv[((size_t)(g * 4) + c) * KK + j]      = sbuf[fin][c][j];
    wsv[((size_t)(g * 4) + c) * KK + j + 64] = sbuf[fin][c][j + 64];
  }
}

// K2: per batch: logZ2 = M7 + log2(sum w7) + telescoped junction corrections.
__global__ __launch_bounds__(256) void crf_combine_kernel(
    const unsigned short* __restrict__ wsv, const float* __restrict__ wsm,
    float* __restrict__ out) {
  const float LN2 = 0.6931471805599453f;
  const int tid = threadIdx.x;
  const int lane = tid & 63, wid = tid >> 6;
  const int b = blockIdx.x * 4 + wid;      // 128 blocks x 4 waves = 512
  const int g = b >> 2, c = b & 3;
  const unsigned short* v7 = wsv + ((size_t)(g * 4) + c) * KK;
  float sum = bf2f(v7[lane]) + bf2f(v7[lane + 64]);
  #pragma unroll
  for (int off = 32; off; off >>= 1) sum += __shfl_xor(sum, off, 64);
  if (lane == 0) {
    auto SC = [&](int s, int k) {
      return wsm[(((size_t)(g * 8 + s)) * 4 + c) * 8 + k];
    };
    float logZ2 = SC(7, 2) + __builtin_amdgcn_logf(sum);   // v_log = log2
    #pragma unroll
    for (int s = 1; s < 8; ++s) {
      logZ2 += SC(s - 1, 2) + __builtin_amdgcn_logf(SC(s - 1, 3));
      logZ2 -= SC(s, 0) + __builtin_amdgcn_logf(SC(s, 1));
    }
    out[b] = SC(0, 4) - logZ2 * LN2;
  }
}

extern "C" void kernel_launch(void* const* d_in, const int* in_sizes, int n_in,
                              void* d_out, int out_size, void* d_ws, size_t ws_size,
                              hipStream_t stream) {
  const float* pot = (const float*)d_in[0];
  const int* tags = (const int*)d_in[1];
  const float* trans = (const float*)d_in[2];
  float* out = (float*)d_out;
  unsigned short* wsv = (unsigned short*)d_ws;                  // 512 x 128 bf16
  float* wsm = (float*)((char*)d_ws + (size_t)512 * KK * 2);    // 1024x4 x 8 f32
  crf_seg_kernel<<<1024, 256, 0, stream>>>(pot, tags, trans, wsv, wsm);
  crf_combine_kernel<<<BB / 4, 256, 0, stream>>>(wsv, wsm, out);
}

// Round 23
// 74.246 us; speedup vs baseline: 1.5002x; 1.0082x over previous
//
#include <hip/hip_runtime.h>

#define BB 512
#define TT 512
#define KK 128
#define CS 144    // chain stride in shorts: 72 dw == +8 banks per chain -> uniform 2-way
#define WARM 4    // warmup steps; contraction 0.151^4 ~ 5e-4 nats: negligible
#define CUT 64    // segment length

typedef __attribute__((ext_vector_type(8))) short short8;   // 8 x bf16 bits
typedef __attribute__((ext_vector_type(4))) float f32x4;

// f32 -> bf16 bits, round-to-nearest-even (finite values)
__device__ __forceinline__ unsigned short f2bf(float f) {
  unsigned u = __float_as_uint(f);
  unsigned r = ((u >> 16) & 1u) + 0x7fffu;
  return (unsigned short)((u + r) >> 16);
}
__device__ __forceinline__ float bf2f(unsigned short h) {
  return __uint_as_float(((unsigned)h) << 16);
}
// Drain LDS ops only; global prefetch loads stay in flight across the barrier.
__device__ __forceinline__ void lds_barrier() {
  asm volatile("s_waitcnt lgkmcnt(0)\n\ts_barrier" ::: "memory");
}

// K1: one block per (batch-quad g, segment s). 256 threads = 4 waves.
// (R22 structure, verified 74.85 us / absmax 16.) Changes:
//  - ADJACENT-COL permutation: wave wv's two tiles map to cols 32wv+2lc and
//    32wv+2lc+1 -> per lane ONE dwordx2 pot load, ONE v_cvt_pk_bf16_f32
//    (replaces 2x 4-op manual rounding), ONE ds_write_b32 (was 2x b16).
//    State stays j-ordered in LDS; read side / d-readlane / exports unchanged.
//  - WARM 8->4 (0.151^4 ~ 5e-4 nats junction error, negligible).
//  - NO s_setprio (suspected barrier-skew amplifier at 4 blocks/SIMD).
// FOUR chains packed into MFMA A-rows: A[row][k] = state[row&3][k].
// D layout: row = 4*(lane>>4)+reg -> chain = reg. Lane (wv,lg,lc) finalizes
// chain lg, cols 32wv+2lc (tile 2wv) and 32wv+2lc+1 (tile 2wv+1).
// Scaled bf16 state in LDS (stride CS=144, 2-way banks); lagged power-of-2
// rescale: stored_new = matvec * 2^(pot*C - d_c), d_c = exponent of
// state[c][0] (readlane from A0 bf16 bits); M_c += d_c. Junctions telescope
// in K2 via (M, state[0]) at warmup-end ("mid") and segment end.
__global__ __launch_bounds__(256, 4) void crf_seg_kernel(
    const float* __restrict__ pot, const int* __restrict__ tags,
    const float* __restrict__ trans, unsigned short* __restrict__ wsv,
    float* __restrict__ wsm) {
  const float C = 1.4426950408889634f;    // 1/ln2
  const int bid = blockIdx.x;
  const int g = bid >> 3, s = bid & 7;    // batch-quad, segment
  const int tid = threadIdx.x;            // 0..255
  const int lane = tid & 63;
  const int wv = tid >> 6;                // wave -> col-tiles 2wv, 2wv+1
  const int lg = lane >> 4;               // lane group = epilogue chain
  const int lc = lane & 15;               // col within 16-tile
  const int crA = lc & 3;                 // A-row chain

  __shared__ alignas(16) unsigned short sbuf[2][4][CS];  // [parity][chain][j]

  // ---- sequence scores: s==0 blocks only; wave wv covers batch 4g+wv ----
  if (s == 0) {
    int bb = 4 * g + wv;
    int base = 8 * lane;
    const float* pbs = pot + (size_t)bb * TT * KK;
    int4 tgA = *(const int4*)&tags[bb * TT + base];
    int4 tgB = *(const int4*)&tags[bb * TT + base + 4];
    float sc =
        pbs[(size_t)(base + 0) * KK + tgA.x] + pbs[(size_t)(base + 1) * KK + tgA.y] +
        pbs[(size_t)(base + 2) * KK + tgA.z] + pbs[(size_t)(base + 3) * KK + tgA.w] +
        pbs[(size_t)(base + 4) * KK + tgB.x] + pbs[(size_t)(base + 5) * KK + tgB.y] +
        pbs[(size_t)(base + 6) * KK + tgB.z] + pbs[(size_t)(base + 7) * KK + tgB.w];
    sc += trans[tgA.x * KK + tgA.y] + trans[tgA.y * KK + tgA.z] +
          trans[tgA.z * KK + tgA.w] + trans[tgA.w * KK + tgB.x] +
          trans[tgB.x * KK + tgB.y] + trans[tgB.y * KK + tgB.z] +
          trans[tgB.z * KK + tgB.w];
    if (base + 8 < TT) sc += trans[tgB.w * KK + tags[bb * TT + base + 8]];
    #pragma unroll
    for (int off = 32; off; off >>= 1) sc += __shfl_xor(sc, off, 64);
    if (lane == 0) wsm[((size_t)bid * 4 + wv) * 8 + 4] = sc;
  }

  // ---- B fragments: tile t covers col 32wv + 2lc + t (adjacent-col perm) ----
  short8 Bf[2][4];
  const int jP = 32 * wv + 2 * lc;        // this lane's even output column
  #pragma unroll
  for (int t = 0; t < 2; ++t) {
    const int j = jP + t;
    #pragma unroll
    for (int kc = 0; kc < 4; ++kc) {
      #pragma unroll
      for (int e = 0; e < 8; ++e) {
        int k = 32 * kc + 8 * lg + e;
        Bf[t][kc][e] = (short)f2bf(__builtin_amdgcn_exp2f(trans[k * KK + j] * C));
      }
    }
  }

  // ---- init: s==0 from u_0; s>0 from all-ones (bf16 1.0) ----
  {
    int c = tid >> 6, j = tid & 63;
    if (s == 0) {
      const float* pi = pot + (size_t)(4 * g + c) * TT * KK;   // row 0
      sbuf[0][c][j]      = f2bf(__builtin_amdgcn_exp2f(pi[j] * C));
      sbuf[0][c][j + 64] = f2bf(__builtin_amdgcn_exp2f(pi[j + 64] * C));
    } else {
      sbuf[0][c][j] = 0x3F80;
      sbuf[0][c][j + 64] = 0x3F80;
    }
  }
  __syncthreads();

  const int r0 = (s == 0) ? 1 : (CUT * s - WARM + 1);
  const float* pp = pot + (size_t)(4 * g + lg) * TT * KK + jP; // chain lg's pot
  int Mi = 0;
  float lastVA = 1.f;
  const f32x4 kZero = {0.f, 0.f, 0.f, 0.f};

  // 4-phase pot pipeline, one float2 per phase (adjacent cols jP, jP+1)
  float2 p0 = *(const float2*)&pp[(size_t)(r0 + 0) * KK];
  float2 p1 = *(const float2*)&pp[(size_t)(r0 + 1) * KK];
  float2 p2 = *(const float2*)&pp[(size_t)(r0 + 2) * KK];
  float2 p3 = *(const float2*)&pp[(size_t)(r0 + 3) * KK];

  auto step = [&](int it, float2& q) {
    const int p = it & 1, wr = p ^ 1;
    const unsigned short* sp = &sbuf[p][crA][8 * lg];
    short8 A0 = *(const short8*)(sp);        // k =      8lg+e
    short8 A1 = *(const short8*)(sp + 32);   // k = 32 + 8lg+e
    short8 A2 = *(const short8*)(sp + 64);
    short8 A3 = *(const short8*)(sp + 96);
    // d_c = exponent of state[c][0]; lanes 0..3 (lg=0, lc=0..3) hold them
    int e0 = (int)(unsigned short)A0[0];
    int d0 = ((__builtin_amdgcn_readlane(e0, 0) >> 7) & 0xFF) - 127;
    int d1 = ((__builtin_amdgcn_readlane(e0, 1) >> 7) & 0xFF) - 127;
    int d2 = ((__builtin_amdgcn_readlane(e0, 2) >> 7) & 0xFF) - 127;
    int d3 = ((__builtin_amdgcn_readlane(e0, 3) >> 7) & 0xFF) - 127;
    float2 cp = q;                           // pot loaded 4 steps ago
    int rn = r0 + it + 4;
    rn = (rn > TT - 1) ? (TT - 1) : rn;      // s==7 tail clamp
    q = *(const float2*)&pp[(size_t)rn * KK];
    f32x4 aP0, aQ0, aP1, aQ1;                // 2 tiles x two 2-deep chains
    aP0 = __builtin_amdgcn_mfma_f32_16x16x32_bf16(A3, Bf[0][3], kZero, 0, 0, 0);
    aQ0 = __builtin_amdgcn_mfma_f32_16x16x32_bf16(A1, Bf[0][1], kZero, 0, 0, 0);
    aP1 = __builtin_amdgcn_mfma_f32_16x16x32_bf16(A3, Bf[1][3], kZero, 0, 0, 0);
    aQ1 = __builtin_amdgcn_mfma_f32_16x16x32_bf16(A1, Bf[1][1], kZero, 0, 0, 0);
    aP0 = __builtin_amdgcn_mfma_f32_16x16x32_bf16(A2, Bf[0][2], aP0, 0, 0, 0);
    aQ0 = __builtin_amdgcn_mfma_f32_16x16x32_bf16(A0, Bf[0][0], aQ0, 0, 0, 0);
    aP1 = __builtin_amdgcn_mfma_f32_16x16x32_bf16(A2, Bf[1][2], aP1, 0, 0, 0);
    aQ1 = __builtin_amdgcn_mfma_f32_16x16x32_bf16(A0, Bf[1][0], aQ1, 0, 0, 0);
    f32x4 s0 = aP0 + aQ0, s1 = aP1 + aQ1;
    // D reg r = chain r; this lane takes chain lg (col jP from s0, jP+1 from s1)
    float zA = (lg == 0) ? s0[0] : ((lg == 1) ? s0[1] : ((lg == 2) ? s0[2] : s0[3]));
    float zB = (lg == 0) ? s1[0] : ((lg == 1) ? s1[1] : ((lg == 2) ? s1[2] : s1[3]));
    int dc = (lg == 0) ? d0 : ((lg == 1) ? d1 : ((lg == 2) ? d2 : d3));
    float fd = (float)(-dc);
    float vA = zA * __builtin_amdgcn_exp2f(fmaf(cp.x, C, fd));
    float vB = zB * __builtin_amdgcn_exp2f(fmaf(cp.y, C, fd));
    Mi += dc;
    lastVA = vA;                             // lane (wv0,lc0): col 0 of chain lg
    unsigned pk;
    asm("v_cvt_pk_bf16_f32 %0, %1, %2" : "=v"(pk) : "v"(vA), "v"(vB));
    *(unsigned*)&sbuf[wr][lg][jP] = pk;      // cols jP (lo), jP+1 (hi)
    lds_barrier();   // lgkmcnt(0)+s_barrier; global loads stay in flight
  };

  // ---- warmup (s>0): 4 steps, then capture the "mid" junction values ----
  float vMid = 1.f; int MiMid = 0;
  if (s > 0) {
    step(0, p0);
    step(1, p1);
    step(2, p2);
    step(3, p3);
    vMid = lastVA; MiMid = Mi;     // state w_{64s} (shifted), scale M
  }
  // ---- main segment: 64 steps (s<7) / 63 steps (s==7) ----
  const int base2 = (s > 0) ? WARM : 0;
  const int mainGroups = (s == 7) ? 15 : 16;
  for (int itq = 0; itq < mainGroups; ++itq) {
    int it = base2 + (itq << 2);
    step(it + 0, p0);
    step(it + 1, p1);
    step(it + 2, p2);
    step(it + 3, p3);
  }
  if (s == 7) {                    // tail: 3 steps (t = 509, 510, 511)
    step(base2 + 60, p0);          // (base2+60) % 4 == 0 -> phase p0
    step(base2 + 61, p1);
    step(base2 + 62, p2);
  }

  // ---- export junction scalars (lanes wv==0, lc==0; lg = chain) ----
  if (wv == 0 && lc == 0) {
    size_t ci = ((size_t)bid * 4 + lg) * 8;
    wsm[ci + 0] = (float)MiMid;    // M at warmup end (s>0)
    wsm[ci + 1] = vMid;            // state[0] at warmup end (s>0)
    wsm[ci + 2] = (float)Mi;       // M at segment end
    wsm[ci + 3] = lastVA;          // state[0] at segment end
  }
  // ---- s==7: export final state vector for the LSE ----
  if (s == 7) {
    const int nst = WARM + 63;     // 67 -> final parity 1
    const int fin = nst & 1;
    int c = tid >> 6, j = tid & 63;
    wsv[((size_t)(g * 4) + c) * KK + j]      = sbuf[fin][c][j];
    wsv[((size_t)(g * 4) + c) * KK + j + 64] = sbuf[fin][c][j + 64];
  }
}

// K2: per batch: logZ2 = M7 + log2(sum w7) + telescoped junction corrections.
__global__ __launch_bounds__(256) void crf_combine_kernel(
    const unsigned short* __restrict__ wsv, const float* __restrict__ wsm,
    float* __restrict__ out) {
  const float LN2 = 0.6931471805599453f;
  const int tid = threadIdx.x;
  const int lane = tid & 63, wid = tid >> 6;
  const int b = blockIdx.x * 4 + wid;      // 128 blocks x 4 waves = 512
  const int g = b >> 2, c = b & 3;
  const unsigned short* v7 = wsv + ((size_t)(g * 4) + c) * KK;
  float sum = bf2f(v7[lane]) + bf2f(v7[lane + 64]);
  #pragma unroll
  for (int off = 32; off; off >>= 1) sum += __shfl_xor(sum, off, 64);
  if (lane == 0) {
    auto SC = [&](int s, int k) {
      return wsm[(((size_t)(g * 8 + s)) * 4 + c) * 8 + k];
    };
    float logZ2 = SC(7, 2) + __builtin_amdgcn_logf(sum);   // v_log = log2
    #pragma unroll
    for (int s = 1; s < 8; ++s) {
      logZ2 += SC(s - 1, 2) + __builtin_amdgcn_logf(SC(s - 1, 3));
      logZ2 -= SC(s, 0) + __builtin_amdgcn_logf(SC(s, 1));
    }
    out[b] = SC(0, 4) - logZ2 * LN2;
  }
}

extern "C" void kernel_launch(void* const* d_in, const int* in_sizes, int n_in,
                              void* d_out, int out_size, void* d_ws, size_t ws_size,
                              hipStream_t stream) {
  const float* pot = (const float*)d_in[0];
  const int* tags = (const int*)d_in[1];
  const float* trans = (const float*)d_in[2];
  float* out = (float*)d_out;
  unsigned short* wsv = (unsigned short*)d_ws;                  // 512 x 128 bf16
  float* wsm = (float*)((char*)d_ws + (size_t)512 * KK * 2);    // 1024x4 x 8 f32
  crf_seg_kernel<<<1024, 256, 0, stream>>>(pot, tags, trans, wsv, wsm);
  crf_combine_kernel<<<BB / 4, 256, 0, stream>>>(wsv, wsm, out);
}